// Round 10
// baseline (324.757 us; speedup 1.0000x reference)
//
#include <hip/hip_runtime.h>

#define EPS 1e-6f

constexpr int Bn = 4096;   // batch rows
constexpr int Dn = 1024;   // feature dim
constexpr int Kn = 4096;   // codebook entries

typedef __attribute__((ext_vector_type(4))) float f32x4;      // MFMA accumulator
typedef __attribute__((ext_vector_type(8))) int   i32x8;      // 32B fp8 fragment
typedef __attribute__((ext_vector_type(2))) long long ll2;    // 16B granule

// 'hi' operand of cvt_pk_fp8 must be an immediate — two literal wrappers.
__device__ inline int pk_fp8_lo(float a, float b, int old) {
    return __builtin_amdgcn_cvt_pk_fp8_f32(a, b, old, false);  // HW RNE e4m3
}
__device__ inline int pk_fp8_hi(float a, float b, int old) {
    return __builtin_amdgcn_cvt_pk_fp8_f32(a, b, old, true);
}

// pack candidate k (12 bits) into low mantissa of positive score s.
// Monotone in s (|error| <= ~1 at s~2048), ties break to smaller k.
__device__ inline float packcand(float s, int k) {
    unsigned b = __float_as_uint(fmaxf(s, 0.5f));
    return __uint_as_float((b & 0xFFFFF000u) | (unsigned)k);
}

// ---- fused prep: phase A (bid<2048) x->fp8 + row stats;                   -
// ----             phase B (bid>=2048) w transpose (fp32 + fp8) + col stats -
__global__ __launch_bounds__(256) void som_prep(
    const float* __restrict__ x, const float* __restrict__ w,
    unsigned char* __restrict__ xf8, float* __restrict__ rrow,
    float* __restrict__ wtf, unsigned char* __restrict__ wf8,
    float* __restrict__ cpart) {
    __shared__ float t[64][65];
    __shared__ float cp[4][64];
    __shared__ float red[8];
    const int tid = threadIdx.x;
    const int bid = blockIdx.x;
    if (bid < 2048) {
        const int lane = tid & 63, wid = tid >> 6;
        size_t i = (size_t)bid * 256 + tid;          // 8 elems / thread
        const float4* p = (const float4*)x;
        float4 a = p[i * 2], b = p[i * 2 + 1];
        int lo = pk_fp8_lo(a.x, a.y, 0); lo = pk_fp8_hi(a.z, a.w, lo);
        int hi = pk_fp8_lo(b.x, b.y, 0); hi = pk_fp8_hi(b.z, b.w, hi);
        ((int2*)xf8)[i] = make_int2(lo, hi);
        float s2 = a.x*a.x + a.y*a.y + a.z*a.z + a.w*a.w
                 + b.x*b.x + b.y*b.y + b.z*b.z + b.w*b.w;
        float s1 = a.x + a.y + a.z + a.w + b.x + b.y + b.z + b.w;
        #pragma unroll
        for (int off = 1; off < 64; off <<= 1) {
            s2 += __shfl_xor(s2, off);
            s1 += __shfl_xor(s1, off);
        }
        if (lane == 0) { red[wid] = s2; red[4 + wid] = s1; }
        __syncthreads();
        if (tid == 0)
            rrow[bid * 2] = (red[0] + red[1])
                + 2.f * EPS * (red[4] + red[5]) + (float)Dn * EPS * EPS;
        if (tid == 128)
            rrow[bid * 2 + 1] = (red[2] + red[3])
                + 2.f * EPS * (red[6] + red[7]) + (float)Dn * EPS * EPS;
    } else {
        const int tb = bid - 2048;
        const int kb = tb & 63, db = tb >> 6;        // 64 k-blocks x 16 d-blocks
        const int k0 = kb * 64, d0 = db * 64;
        const int tx = tid & 63, ty = tid >> 6;
        #pragma unroll
        for (int i = 0; i < 16; ++i) {
            int d = i * 4 + ty;
            t[d][tx] = w[(size_t)(d0 + d) * Kn + k0 + tx];   // 256 B coalesced
        }
        __syncthreads();
        #pragma unroll
        for (int i = 0; i < 16; ++i) {
            int kr = i * 4 + ty;
            float v = t[tx][kr];                     // stride 65: conflict-free
            wtf[(size_t)(k0 + kr) * Dn + d0 + tx] = v;
            wf8[(size_t)(k0 + kr) * Dn + d0 + tx] =
                (unsigned char)(pk_fp8_lo(v, v, 0) & 0xFF);
        }
        // column-stat partial over this block's 64 d: sum (w^2 - 2 eps w)
        float cs = 0.f;
        #pragma unroll
        for (int j = 0; j < 16; ++j) {
            float v = t[ty * 16 + j][tx];
            cs = fmaf(v, v - 2.f * EPS, cs);
        }
        cp[ty][tx] = cs;
        __syncthreads();
        if (ty == 0)
            cpart[(size_t)db * Kn + k0 + tx] = cp[0][tx] + cp[1][tx] + cp[2][tx] + cp[3][tx];
    }
}

// ---- fp8 screen GEMM via MX-scaled MFMA K=128 with unit scales ------------
// Scales = e8m0 127 (2^0): bit-identical to non-scaled fp8 math, but 2x the
// MFMA rate and 4x fewer instructions. A/B operand k-maps are identical for
// both sides, so plain row-major LDS [row][d] (stride 144 B pad) is correct
// for ANY hardware (quad,byte)->k bijection. Staging = 1 ds_write_b128 per
// 16B granule; fragments = contiguous 32 B per tile (2x ds_read_b128).
__global__ __launch_bounds__(256, 3) void som_gemm_fp8(
    const unsigned char* __restrict__ xf8, const unsigned char* __restrict__ wf8,
    const float* __restrict__ cpart, float* __restrict__ pval) {
    __shared__ __align__(16) unsigned char As[128 * 144];
    __shared__ __align__(16) unsigned char Bs[128 * 144];
    const int tid = threadIdx.x;
    const int lane = tid & 63;
    const int wid = tid >> 6;
    const int wm = wid >> 1, wn = wid & 1;    // 2x2 waves of 64x64
    const int f = blockIdx.x;
    const int xcd = f & 7;
    const int ib = f >> 3;
    const int rb = xcd * 4 + (ib & 3);
    const int cb = ib >> 2;
    const int rowBase = rb * 128, colBase = cb * 128;

    // granule (r, s): 16 B of global row r at byte s*16 -> LDS row r col s*16
    int offA[4];
    const unsigned char* gsrcA[4];
    const unsigned char* gsrcB[4];
    #pragma unroll
    for (int i = 0; i < 4; ++i) {
        int g = i * 256 + tid;
        int r = g >> 3, s = g & 7;
        offA[i] = r * 144 + s * 16;
        gsrcA[i] = xf8 + (size_t)(rowBase + r) * Dn + s * 16;
        gsrcB[i] = wf8 + (size_t)(colBase + r) * Dn + s * 16;
    }

    f32x4 acc[4][4] = {};
    ll2 ra[4], rbv[4];
    #pragma unroll
    for (int i = 0; i < 4; ++i) {            // prefetch iter 0
        ra[i]  = *(const ll2*)(gsrcA[i]);
        rbv[i] = *(const ll2*)(gsrcB[i]);
    }

    const int mrA = (wm * 64 + (lane & 15)) * 144 + (lane >> 4) * 32;
    const int nrB = (wn * 64 + (lane & 15)) * 144 + (lane >> 4) * 32;

    for (int it = 0; it < 8; ++it) {
        #pragma unroll
        for (int i = 0; i < 4; ++i) {
            *(ll2*)&As[offA[i]] = ra[i];
            *(ll2*)&Bs[offA[i]] = rbv[i];
        }
        __syncthreads();
        if (it < 7) {                         // prefetch next iter's globals
            int d0 = (it + 1) * 128;
            #pragma unroll
            for (int i = 0; i < 4; ++i) {
                ra[i]  = *(const ll2*)(gsrcA[i] + d0);
                rbv[i] = *(const ll2*)(gsrcB[i] + d0);
            }
        }
        i32x8 a8[4], b8[4];
        #pragma unroll
        for (int i = 0; i < 4; ++i) {
            int4 lo = *(const int4*)&As[mrA + i * 16 * 144];
            int4 hi = *(const int4*)&As[mrA + i * 16 * 144 + 16];
            a8[i][0] = lo.x; a8[i][1] = lo.y; a8[i][2] = lo.z; a8[i][3] = lo.w;
            a8[i][4] = hi.x; a8[i][5] = hi.y; a8[i][6] = hi.z; a8[i][7] = hi.w;
            lo = *(const int4*)&Bs[nrB + i * 16 * 144];
            hi = *(const int4*)&Bs[nrB + i * 16 * 144 + 16];
            b8[i][0] = lo.x; b8[i][1] = lo.y; b8[i][2] = lo.z; b8[i][3] = lo.w;
            b8[i][4] = hi.x; b8[i][5] = hi.y; b8[i][6] = hi.z; b8[i][7] = hi.w;
        }
        #pragma unroll
        for (int i = 0; i < 4; ++i)
            #pragma unroll
            for (int j = 0; j < 4; ++j)
                acc[i][j] = __builtin_amdgcn_mfma_scale_f32_16x16x128_f8f6f4(
                    a8[i], b8[j], acc[i][j], 0, 0,
                    0, 0x7F7F7F7F, 0, 0x7F7F7F7F);   // fmt fp8/fp8, scales=1.0
        __syncthreads();
    }

    // epilogue: c[k] from cpart, then packed top-2 per (row, 64-col group)
    const int cn = lane & 15, q = lane >> 4;
    const int nbase = colBase + wn * 64;
    float cv[4];
    #pragma unroll
    for (int j = 0; j < 4; ++j) {
        float s = 0.f;
        #pragma unroll
        for (int db = 0; db < 16; ++db)
            s += cpart[(size_t)db * Kn + nbase + j * 16 + cn];
        cv[j] = s;
    }
    #pragma unroll
    for (int i = 0; i < 4; ++i) {
        #pragma unroll
        for (int rg = 0; rg < 4; ++rg) {
            float p1 = 3.4e38f, p2 = 3.4e38f;
            #pragma unroll
            for (int j = 0; j < 4; ++j) {
                float p = packcand(fmaf(-2.f, acc[i][j][rg], cv[j]),
                                   nbase + j * 16 + cn);
                float lo = fminf(p1, p), hi = fmaxf(p1, p);
                p1 = lo; p2 = fminf(p2, hi);
            }
            #pragma unroll
            for (int off = 1; off < 16; off <<= 1) {
                float o1 = __shfl_xor(p1, off);
                float o2 = __shfl_xor(p2, off);
                float lo = fminf(p1, o1), hi = fmaxf(p1, o1);
                p1 = lo; p2 = fminf(hi, fminf(p2, o2));
            }
            if (cn == 0) {
                int mrow = rowBase + wm * 64 + i * 16 + q * 4 + rg;
                size_t e = (size_t)mrow * 128 + cb * 4 + wn * 2;
                pval[e] = p1; pval[e + 1] = p2;
            }
        }
    }
}

// ---- finalize: per row, exact fp32 rescore of all candidates in margin ----
__global__ __launch_bounds__(256) void som_finalize(
    const float* __restrict__ x, const float* __restrict__ wtf,
    const float* __restrict__ cpart, const float* __restrict__ loc,
    const float* __restrict__ pval, const float* __restrict__ rrow,
    float* __restrict__ dist, float* __restrict__ out) {
    const int lane = threadIdx.x & 63;
    const int row = blockIdx.x * 4 + (threadIdx.x >> 6);

    const float4* xr = (const float4*)(x + (size_t)row * Dn);
    float4 xv[4];
    #pragma unroll
    for (int j = 0; j < 4; ++j) xv[j] = xr[lane * 4 + j];
    const float rrv = rrow[row];

    float v0 = pval[(size_t)row * 128 + lane];
    float v1 = pval[(size_t)row * 128 + 64 + lane];
    float g = fminf(v0, v1);
    #pragma unroll
    for (int off = 1; off < 64; off <<= 1) g = fminf(g, __shfl_xor(g, off));
    const float thr = g + 30.0f;  // fp8 screen noise (sigma~2.7) + pack error
    unsigned long long m0 = __ballot(v0 <= thr);
    unsigned long long m1 = __ballot(v1 <= thr);

    float bestd2 = 3.4e38f; int bestk = 0x7fffffff;
    #pragma unroll
    for (int slot = 0; slot < 2; ++slot) {
        unsigned long long m = slot ? m1 : m0;
        float vs = slot ? v1 : v0;
        while (m) {
            int src = __builtin_ctzll(m); m &= m - 1;
            int k = ((int)__float_as_uint(__shfl(vs, src))) & 0xFFF;
            const float4* wr = (const float4*)(wtf + (size_t)k * Dn);
            float dt = 0.f;
            #pragma unroll
            for (int j = 0; j < 4; ++j) {
                float4 wv = wr[lane * 4 + j];
                dt += xv[j].x * wv.x + xv[j].y * wv.y + xv[j].z * wv.z + xv[j].w * wv.w;
            }
            #pragma unroll
            for (int off = 1; off < 64; off <<= 1) dt += __shfl_xor(dt, off);
            float ck = 0.f;
            #pragma unroll
            for (int db = 0; db < 16; ++db) ck += cpart[(size_t)db * Kn + k];
            float d2 = rrv + ck - 2.f * dt;
            if (d2 < bestd2 || (d2 == bestd2 && k < bestk)) { bestd2 = d2; bestk = k; }
        }
    }
    if (lane == 0) {
        out[2 * row]     = loc[2 * bestk];
        out[2 * row + 1] = loc[2 * bestk + 1];
        out[8193 + row]  = (float)bestk;
        dist[row]        = sqrtf(fmaxf(bestd2, 0.f));
    }
}

// ---- loss: single block reduces the 4096 per-row distances ----------------
__global__ __launch_bounds__(256) void som_loss(const float* __restrict__ dist,
                                                float* __restrict__ out) {
    __shared__ float red[4];
    const int tid = threadIdx.x;
    const int lane = tid & 63, wid = tid >> 6;
    const float4* p = (const float4*)dist;
    float s = 0.f;
    #pragma unroll
    for (int j = 0; j < 4; ++j) {
        float4 v = p[tid + j * 256];
        s += v.x + v.y + v.z + v.w;
    }
    #pragma unroll
    for (int off = 1; off < 64; off <<= 1) s += __shfl_xor(s, off);
    if (lane == 0) red[wid] = s;
    __syncthreads();
    if (tid == 0)
        out[8192] = (red[0] + red[1] + red[2] + red[3]) * (1.0f / (float)Bn);
}

extern "C" void kernel_launch(void* const* d_in, const int* in_sizes, int n_in,
                              void* d_out, int out_size, void* d_ws, size_t ws_size,
                              hipStream_t stream) {
    const float* x   = (const float*)d_in[0];   // [B, D]
    const float* w   = (const float*)d_in[1];   // [D, K]
    const float* loc = (const float*)d_in[2];   // [K, 2]
    float* out = (float*)d_out;

    float* rrow = (float*)d_ws;                            // 16 KB  [B]
    float* wtf  = rrow + Bn;                               // 16 MB  [K][D] fp32
    unsigned char* wf8 = (unsigned char*)(wtf + (size_t)Kn * Dn);  // 4 MB
    unsigned char* xf8 = wf8 + (size_t)Kn * Dn;            // 4 MB
    float* pval = (float*)(xf8 + (size_t)Bn * Dn);         // 2 MB packed top-2
    float* cpart = pval + (size_t)Bn * 128;                // 256 KB [16][K]
    float* dist  = cpart + 16 * Kn;                        // 16 KB  [B]

    som_prep<<<3072, 256, 0, stream>>>(x, w, xf8, rrow, wtf, wf8, cpart);
    som_gemm_fp8<<<1024, 256, 0, stream>>>(xf8, wf8, cpart, pval);
    som_finalize<<<Bn / 4, 256, 0, stream>>>(x, wtf, cpart, loc, pval, rrow, dist, out);
    som_loss<<<1, 256, 0, stream>>>(dist, out);
}

// Round 11
// 142.541 us; speedup vs baseline: 2.2783x; 2.2783x over previous
//
#include <hip/hip_runtime.h>

#define EPS 1e-6f

constexpr int Bn = 4096;   // batch rows
constexpr int Dn = 1024;   // feature dim
constexpr int Kn = 4096;   // codebook entries

typedef __attribute__((ext_vector_type(4))) float f32x4;      // MFMA accumulator
typedef __attribute__((ext_vector_type(2))) long long ll2;    // 16B = 2 fp8 k-slices

// 'hi' operand of cvt_pk_fp8 must be an immediate — two literal wrappers.
__device__ inline int pk_fp8_lo(float a, float b, int old) {
    return __builtin_amdgcn_cvt_pk_fp8_f32(a, b, old, false);  // HW RNE e4m3
}
__device__ inline int pk_fp8_hi(float a, float b, int old) {
    return __builtin_amdgcn_cvt_pk_fp8_f32(a, b, old, true);
}

// pack candidate k (12 bits) into low mantissa of positive score s.
// Monotone in s (|error| <= ~1 at s~2048), ties break to smaller k.
__device__ inline float packcand(float s, int k) {
    unsigned b = __float_as_uint(fmaxf(s, 0.5f));
    return __uint_as_float((b & 0xFFFFF000u) | (unsigned)k);
}

// ---- fused prep: phase A (bid<2048) x->fp8 + row stats;                   -
// ----             phase B (bid>=2048) w transpose (fp32 + fp8) + col stats -
__global__ __launch_bounds__(256) void som_prep(
    const float* __restrict__ x, const float* __restrict__ w,
    unsigned char* __restrict__ xf8, float* __restrict__ rrow,
    float* __restrict__ wtf, unsigned char* __restrict__ wf8,
    float* __restrict__ cpart) {
    __shared__ float t[64][65];
    __shared__ float cp[4][64];
    __shared__ float red[8];
    const int tid = threadIdx.x;
    const int bid = blockIdx.x;
    if (bid < 2048) {
        const int lane = tid & 63, wid = tid >> 6;
        size_t i = (size_t)bid * 256 + tid;          // 8 elems / thread
        const float4* p = (const float4*)x;
        float4 a = p[i * 2], b = p[i * 2 + 1];
        int lo = pk_fp8_lo(a.x, a.y, 0); lo = pk_fp8_hi(a.z, a.w, lo);
        int hi = pk_fp8_lo(b.x, b.y, 0); hi = pk_fp8_hi(b.z, b.w, hi);
        ((int2*)xf8)[i] = make_int2(lo, hi);
        float s2 = a.x*a.x + a.y*a.y + a.z*a.z + a.w*a.w
                 + b.x*b.x + b.y*b.y + b.z*b.z + b.w*b.w;
        float s1 = a.x + a.y + a.z + a.w + b.x + b.y + b.z + b.w;
        #pragma unroll
        for (int off = 1; off < 64; off <<= 1) {
            s2 += __shfl_xor(s2, off);
            s1 += __shfl_xor(s1, off);
        }
        if (lane == 0) { red[wid] = s2; red[4 + wid] = s1; }
        __syncthreads();
        if (tid == 0)
            rrow[bid * 2] = (red[0] + red[1])
                + 2.f * EPS * (red[4] + red[5]) + (float)Dn * EPS * EPS;
        if (tid == 128)
            rrow[bid * 2 + 1] = (red[2] + red[3])
                + 2.f * EPS * (red[6] + red[7]) + (float)Dn * EPS * EPS;
    } else {
        const int tb = bid - 2048;
        const int kb = tb & 63, db = tb >> 6;        // 64 k-blocks x 16 d-blocks
        const int k0 = kb * 64, d0 = db * 64;
        const int tx = tid & 63, ty = tid >> 6;
        #pragma unroll
        for (int i = 0; i < 16; ++i) {
            int d = i * 4 + ty;
            t[d][tx] = w[(size_t)(d0 + d) * Kn + k0 + tx];   // 256 B coalesced
        }
        __syncthreads();
        #pragma unroll
        for (int i = 0; i < 16; ++i) {
            int kr = i * 4 + ty;
            float v = t[tx][kr];                     // stride 65: conflict-free
            wtf[(size_t)(k0 + kr) * Dn + d0 + tx] = v;
            wf8[(size_t)(k0 + kr) * Dn + d0 + tx] =
                (unsigned char)(pk_fp8_lo(v, v, 0) & 0xFF);
        }
        // column-stat partial over this block's 64 d: sum (w^2 - 2 eps w)
        float cs = 0.f;
        #pragma unroll
        for (int j = 0; j < 16; ++j) {
            float v = t[ty * 16 + j][tx];
            cs = fmaf(v, v - 2.f * EPS, cs);
        }
        cp[ty][tx] = cs;
        __syncthreads();
        if (ty == 0)
            cpart[(size_t)db * Kn + k0 + tx] = cp[0][tx] + cp[1][tx] + cp[2][tx] + cp[3][tx];
    }
}

// ---- fp8 MFMA screen GEMM: BK=128, padded q-major LDS, top-2/64-col group -
// LDS layout: row stride 144 B (pad kills conflicts); within row the d index
// d = kk*32 + q*8 + j is stored at column q*32 + kk*8 + j so one lane's four
// k-slices are contiguous 32 B (2x ds_read_b128 per fragment set).
// NOTE (R10 post-mortem): do NOT switch to mfma_scale_*_f8f6f4 here — the
// v8i32 operand marshalling spills to scratch (355 MB writes, 4x slowdown).
__global__ __launch_bounds__(256, 3) void som_gemm_fp8(
    const unsigned char* __restrict__ xf8, const unsigned char* __restrict__ wf8,
    const float* __restrict__ cpart, float* __restrict__ pval) {
    __shared__ __align__(16) unsigned char As[128 * 144];
    __shared__ __align__(16) unsigned char Bs[128 * 144];
    const int tid = threadIdx.x;
    const int lane = tid & 63;
    const int wid = tid >> 6;
    const int wm = wid >> 1, wn = wid & 1;    // 2x2 waves of 64x64
    const int f = blockIdx.x;
    const int xcd = f & 7;
    const int ib = f >> 3;
    const int rb = xcd * 4 + (ib & 3);
    const int cb = ib >> 2;
    const int rowBase = rb * 128, colBase = cb * 128;

    // granule (r, s): 16 B of global row r at byte s*16; covers kk=s>>1,
    // q = 2*(s&1)+{0,1}. LDS dst: off_a (first 8B), off_a+32 (second 8B).
    int offA[4];
    const unsigned char* gsrcA[4];
    const unsigned char* gsrcB[4];
    #pragma unroll
    for (int i = 0; i < 4; ++i) {
        int g = i * 256 + tid;
        int r = g >> 3, s = g & 7;
        offA[i] = r * 144 + (2 * (s & 1)) * 32 + (s >> 1) * 8;
        gsrcA[i] = xf8 + (size_t)(rowBase + r) * Dn + s * 16;
        gsrcB[i] = wf8 + (size_t)(colBase + r) * Dn + s * 16;
    }

    f32x4 acc[4][4] = {};
    ll2 ra[4], rbv[4];
    #pragma unroll
    for (int i = 0; i < 4; ++i) {            // prefetch iter 0
        ra[i]  = *(const ll2*)(gsrcA[i]);
        rbv[i] = *(const ll2*)(gsrcB[i]);
    }

    const int mrA = (wm * 64 + (lane & 15)) * 144;
    const int nrB = (wn * 64 + (lane & 15)) * 144;
    const int qoff = (lane >> 4) * 32;

    for (int it = 0; it < 8; ++it) {
        #pragma unroll
        for (int i = 0; i < 4; ++i) {
            *(long long*)&As[offA[i]]      = ra[i][0];
            *(long long*)&As[offA[i] + 32] = ra[i][1];
            *(long long*)&Bs[offA[i]]      = rbv[i][0];
            *(long long*)&Bs[offA[i] + 32] = rbv[i][1];
        }
        __syncthreads();
        if (it < 7) {                         // prefetch next iter's globals
            int d0 = (it + 1) * 128;
            #pragma unroll
            for (int i = 0; i < 4; ++i) {
                ra[i]  = *(const ll2*)(gsrcA[i] + d0);
                rbv[i] = *(const ll2*)(gsrcB[i] + d0);
            }
        }
        #pragma unroll
        for (int kk2 = 0; kk2 < 2; ++kk2) {
            ll2 a2[4], b2[4];
            #pragma unroll
            for (int i = 0; i < 4; ++i) {
                a2[i] = *(const ll2*)&As[mrA + i * 16 * 144 + qoff + kk2 * 16];
                b2[i] = *(const ll2*)&Bs[nrB + i * 16 * 144 + qoff + kk2 * 16];
            }
            #pragma unroll
            for (int i = 0; i < 4; ++i)
                #pragma unroll
                for (int j = 0; j < 4; ++j) {
                    acc[i][j] = __builtin_amdgcn_mfma_f32_16x16x32_fp8_fp8(
                        a2[i][0], b2[j][0], acc[i][j], 0, 0, 0);
                    acc[i][j] = __builtin_amdgcn_mfma_f32_16x16x32_fp8_fp8(
                        a2[i][1], b2[j][1], acc[i][j], 0, 0, 0);
                }
        }
        __syncthreads();
    }

    // epilogue: c[k] from cpart, then packed top-2 per (row, 64-col group)
    const int cn = lane & 15, q = lane >> 4;
    const int nbase = colBase + wn * 64;
    float cv[4];
    #pragma unroll
    for (int j = 0; j < 4; ++j) {
        float s = 0.f;
        #pragma unroll
        for (int db = 0; db < 16; ++db)
            s += cpart[(size_t)db * Kn + nbase + j * 16 + cn];
        cv[j] = s;
    }
    #pragma unroll
    for (int i = 0; i < 4; ++i) {
        #pragma unroll
        for (int rg = 0; rg < 4; ++rg) {
            float p1 = 3.4e38f, p2 = 3.4e38f;
            #pragma unroll
            for (int j = 0; j < 4; ++j) {
                float p = packcand(fmaf(-2.f, acc[i][j][rg], cv[j]),
                                   nbase + j * 16 + cn);
                float lo = fminf(p1, p), hi = fmaxf(p1, p);
                p1 = lo; p2 = fminf(p2, hi);
            }
            #pragma unroll
            for (int off = 1; off < 16; off <<= 1) {
                float o1 = __shfl_xor(p1, off);
                float o2 = __shfl_xor(p2, off);
                float lo = fminf(p1, o1), hi = fmaxf(p1, o1);
                p1 = lo; p2 = fminf(hi, fminf(p2, o2));
            }
            if (cn == 0) {
                int mrow = rowBase + wm * 64 + i * 16 + q * 4 + rg;
                size_t e = (size_t)mrow * 128 + cb * 4 + wn * 2;
                pval[e] = p1; pval[e + 1] = p2;
            }
        }
    }
}

// ---- finalize: per row, exact fp32 rescore of all candidates in margin ----
__global__ __launch_bounds__(256) void som_finalize(
    const float* __restrict__ x, const float* __restrict__ wtf,
    const float* __restrict__ cpart, const float* __restrict__ loc,
    const float* __restrict__ pval, const float* __restrict__ rrow,
    float* __restrict__ dist, float* __restrict__ out) {
    const int lane = threadIdx.x & 63;
    const int row = blockIdx.x * 4 + (threadIdx.x >> 6);

    const float4* xr = (const float4*)(x + (size_t)row * Dn);
    float4 xv[4];
    #pragma unroll
    for (int j = 0; j < 4; ++j) xv[j] = xr[lane * 4 + j];
    const float rrv = rrow[row];

    float v0 = pval[(size_t)row * 128 + lane];
    float v1 = pval[(size_t)row * 128 + 64 + lane];
    float g = fminf(v0, v1);
    #pragma unroll
    for (int off = 1; off < 64; off <<= 1) g = fminf(g, __shfl_xor(g, off));
    const float thr = g + 30.0f;  // fp8 screen noise (sigma~2.7) + pack error
    unsigned long long m0 = __ballot(v0 <= thr);
    unsigned long long m1 = __ballot(v1 <= thr);

    float bestd2 = 3.4e38f; int bestk = 0x7fffffff;
    #pragma unroll
    for (int slot = 0; slot < 2; ++slot) {
        unsigned long long m = slot ? m1 : m0;
        float vs = slot ? v1 : v0;
        while (m) {
            int src = __builtin_ctzll(m); m &= m - 1;
            int k = ((int)__float_as_uint(__shfl(vs, src))) & 0xFFF;
            const float4* wr = (const float4*)(wtf + (size_t)k * Dn);
            float dt = 0.f;
            #pragma unroll
            for (int j = 0; j < 4; ++j) {
                float4 wv = wr[lane * 4 + j];
                dt += xv[j].x * wv.x + xv[j].y * wv.y + xv[j].z * wv.z + xv[j].w * wv.w;
            }
            #pragma unroll
            for (int off = 1; off < 64; off <<= 1) dt += __shfl_xor(dt, off);
            float ck = 0.f;
            #pragma unroll
            for (int db = 0; db < 16; ++db) ck += cpart[(size_t)db * Kn + k];
            float d2 = rrv + ck - 2.f * dt;
            if (d2 < bestd2 || (d2 == bestd2 && k < bestk)) { bestd2 = d2; bestk = k; }
        }
    }
    if (lane == 0) {
        out[2 * row]     = loc[2 * bestk];
        out[2 * row + 1] = loc[2 * bestk + 1];
        out[8193 + row]  = (float)bestk;
        dist[row]        = sqrtf(fmaxf(bestd2, 0.f));
    }
}

// ---- loss: single block reduces the 4096 per-row distances ----------------
__global__ __launch_bounds__(256) void som_loss(const float* __restrict__ dist,
                                                float* __restrict__ out) {
    __shared__ float red[4];
    const int tid = threadIdx.x;
    const int lane = tid & 63, wid = tid >> 6;
    const float4* p = (const float4*)dist;
    float s = 0.f;
    #pragma unroll
    for (int j = 0; j < 4; ++j) {
        float4 v = p[tid + j * 256];
        s += v.x + v.y + v.z + v.w;
    }
    #pragma unroll
    for (int off = 1; off < 64; off <<= 1) s += __shfl_xor(s, off);
    if (lane == 0) red[wid] = s;
    __syncthreads();
    if (tid == 0)
        out[8192] = (red[0] + red[1] + red[2] + red[3]) * (1.0f / (float)Bn);
}

extern "C" void kernel_launch(void* const* d_in, const int* in_sizes, int n_in,
                              void* d_out, int out_size, void* d_ws, size_t ws_size,
                              hipStream_t stream) {
    const float* x   = (const float*)d_in[0];   // [B, D]
    const float* w   = (const float*)d_in[1];   // [D, K]
    const float* loc = (const float*)d_in[2];   // [K, 2]
    float* out = (float*)d_out;

    float* rrow = (float*)d_ws;                            // 16 KB  [B]
    float* wtf  = rrow + Bn;                               // 16 MB  [K][D] fp32
    unsigned char* wf8 = (unsigned char*)(wtf + (size_t)Kn * Dn);  // 4 MB
    unsigned char* xf8 = wf8 + (size_t)Kn * Dn;            // 4 MB
    float* pval = (float*)(xf8 + (size_t)Bn * Dn);         // 2 MB packed top-2
    float* cpart = pval + (size_t)Bn * 128;                // 256 KB [16][K]
    float* dist  = cpart + 16 * Kn;                        // 16 KB  [B]

    som_prep<<<3072, 256, 0, stream>>>(x, w, xf8, rrow, wtf, wf8, cpart);
    som_gemm_fp8<<<1024, 256, 0, stream>>>(xf8, wf8, cpart, pval);
    som_finalize<<<Bn / 4, 256, 0, stream>>>(x, wtf, cpart, loc, pval, rrow, dist, out);
    som_loss<<<1, 256, 0, stream>>>(dist, out);
}